// Round 1
// baseline (168.595 us; speedup 1.0000x reference)
//
#include <hip/hip_runtime.h>

// QueryEncDec: 2 stacks x 128 layers of scalar GRU (H=in=1), T=256.
// Wavefront parallelization: thread l = global layer l (0..127 enc, 128..255 dec).
// Diagonal s: thread l processes t = s - l. Handoff layer l -> l+1 via
// double-buffered LDS, one __syncthreads per diagonal (511 total).

#define T_LEN   256
#define NLAYERS 256

__device__ __forceinline__ float fexp(float x) {
    // e^x = 2^(x*log2(e)), single v_exp_f32
    return __builtin_amdgcn_exp2f(x * 1.44269504088896340736f);
}
__device__ __forceinline__ float frcp(float x) {
    return __builtin_amdgcn_rcpf(x);
}
__device__ __forceinline__ float fsigmoid(float x) {
    return frcp(1.0f + fexp(-x));
}
__device__ __forceinline__ float ftanh(float x) {
    // 1 - 2/(e^{2x}+1); saturates correctly at +/-1 for large |x|
    return 1.0f - 2.0f * frcp(fexp(2.0f * x) + 1.0f);
}

__global__ __launch_bounds__(256, 1) void gru_wavefront(
    const float* __restrict__ X,
    const float* __restrict__ enc_w_ih, const float* __restrict__ enc_w_hh,
    const float* __restrict__ enc_b_ih, const float* __restrict__ enc_b_hh,
    const float* __restrict__ dec_w_ih, const float* __restrict__ dec_w_hh,
    const float* __restrict__ dec_b_ih, const float* __restrict__ dec_b_hh,
    float* __restrict__ out)
{
    const int l = threadIdx.x;              // global layer index 0..255
    __shared__ float xs[T_LEN];             // staged input sequence
    __shared__ float buf[2][NLAYERS];       // double-buffered layer outputs

    xs[l] = X[l];                           // T_LEN == blockDim.x == 256

    // Per-layer scalar params (torch gate order r,z,n)
    const int pl = l & 127;
    const float* wip = (l < 128) ? enc_w_ih : dec_w_ih;
    const float* whp = (l < 128) ? enc_w_hh : dec_w_hh;
    const float* bip = (l < 128) ? enc_b_ih : dec_b_ih;
    const float* bhp = (l < 128) ? enc_b_hh : dec_b_hh;
    const float wi0 = wip[pl * 3 + 0], wi1 = wip[pl * 3 + 1], wi2 = wip[pl * 3 + 2];
    const float wh0 = whp[pl * 3 + 0], wh1 = whp[pl * 3 + 1], wh2 = whp[pl * 3 + 2];
    const float bi0 = bip[pl * 3 + 0], bi1 = bip[pl * 3 + 1], bi2 = bip[pl * 3 + 2];
    const float bh0 = bhp[pl * 3 + 0], bh1 = bhp[pl * 3 + 1], bh2 = bhp[pl * 3 + 2];

    float h = 0.0f;
    __syncthreads();

    // lane 0 prefetches its next input one step ahead (hides LDS latency)
    float xnext = (l == 0) ? xs[0] : 0.0f;

    const int S = T_LEN + NLAYERS - 1;      // 511 diagonals
    for (int s = 0; s < S; ++s) {
        const float xcur = xnext;
        if (l == 0 && s + 1 < T_LEN) xnext = xs[s + 1];

        const int t = s - l;
        if (0 <= t && t < T_LEN) {
            // input: X for layer 0, else previous layer's output at time t
            // (written by thread l-1 at step s-1, into buffer (s-1)&1)
            const float x = (l == 0) ? xcur : buf[(s - 1) & 1][l - 1];

            const float gh0 = __builtin_fmaf(wh0, h, bh0);
            const float gh1 = __builtin_fmaf(wh1, h, bh1);
            const float gh2 = __builtin_fmaf(wh2, h, bh2);
            const float gi0 = __builtin_fmaf(wi0, x, bi0);
            const float gi1 = __builtin_fmaf(wi1, x, bi1);
            const float gi2 = __builtin_fmaf(wi2, x, bi2);

            const float r = fsigmoid(gi0 + gh0);
            const float z = fsigmoid(gi1 + gh1);
            const float n = ftanh(__builtin_fmaf(r, gh2, gi2));
            h = n + z * (h - n);            // (1-z)*n + z*h

            buf[s & 1][l] = h;
            if (l == NLAYERS - 1) out[t] = h;   // dec_out[t]
        }
        __syncthreads();
    }

    // dec_h: final hidden of decoder layers
    if (l >= 128) out[T_LEN + (l - 128)] = h;
}

extern "C" void kernel_launch(void* const* d_in, const int* in_sizes, int n_in,
                              void* d_out, int out_size, void* d_ws, size_t ws_size,
                              hipStream_t stream) {
    const float* X        = (const float*)d_in[0];
    const float* enc_w_ih = (const float*)d_in[1];
    const float* enc_w_hh = (const float*)d_in[2];
    const float* enc_b_ih = (const float*)d_in[3];
    const float* enc_b_hh = (const float*)d_in[4];
    const float* dec_w_ih = (const float*)d_in[5];
    const float* dec_w_hh = (const float*)d_in[6];
    const float* dec_b_ih = (const float*)d_in[7];
    const float* dec_b_hh = (const float*)d_in[8];
    float* out = (float*)d_out;

    gru_wavefront<<<1, 256, 0, stream>>>(X,
                                         enc_w_ih, enc_w_hh, enc_b_ih, enc_b_hh,
                                         dec_w_ih, dec_w_hh, dec_b_ih, dec_b_hh,
                                         out);
}